// Round 2
// baseline (1007.543 us; speedup 1.0000x reference)
//
#include <hip/hip_runtime.h>
#include <hip/hip_bf16.h>

// RBF-kernel attention, MI355X.  B=8, Q=K=4096, D=256, d=64.
// Outputs (concat fp32): out [8,4096,64] then attn [8,4096,4096].
// R5: K-sliced 4-wave blocks to fix R4's occupancy cap.
//  - R4 post-mortem: 16 rows/wave => only 2048 waves = 2 waves/SIMD; kernel was
//    latency-bound (all pipes <6% busy, 18% HBM). Grid was the ceiling.
//  - R5: block = 4 waves on the SAME 16 q-rows; wave w takes K-tiles nt%4==w
//    (round-robin => balanced, zero-tiles included). 8192 waves = 8/SIMD.
//  - rowsum combine: 256B LDS + 1 barrier. PV combine: 4x [64][17] f32 LDS
//    slabs (+pad => <=2-way bank conflicts) + 1 barrier; each wave then does
//    one quarter (t4o = w) of the Wo epilogue. No barriers inside K-loops.
//  - keeps R4 register layouts: swapped QK^T (mfma(K,Q^T)) so lane owns one
//    q-row's scores; P feeds PV via mfma_16x16x16f16 with 2 cvt_pkrtz, no
//    shuffles; nontemporal attn/zero stores; mask baked into kcw (-inf).

typedef _Float16 HALF;
typedef HALF half8 __attribute__((ext_vector_type(8)));
typedef HALF half4 __attribute__((ext_vector_type(4)));
typedef __fp16 fp16x2 __attribute__((ext_vector_type(2)));
typedef float f32x4 __attribute__((ext_vector_type(4)));

#define MFMA32(a, b, c) __builtin_amdgcn_mfma_f32_16x16x32_f16((a), (b), (c), 0, 0, 0)
#define MFMA16(a, b, c) __builtin_amdgcn_mfma_f32_16x16x16f16((a), (b), (c), 0, 0, 0)

union Cv4 { HALF h[4]; uint2 u; };
union Cv8 { HALF h[8]; uint4 u; };
union PK4 { fp16x2 p2[2]; half4 v; };

// ---------------- kernel 0: W transposes -> f16 ----------------
__global__ __launch_bounds__(256) void k_prep(const float* __restrict__ Wq,
                                              const float* __restrict__ Wk,
                                              const float* __restrict__ Wv,
                                              const float* __restrict__ Wo,
                                              HALF* __restrict__ wt,
                                              HALF* __restrict__ wto) {
    int gid = blockIdx.x * 256 + threadIdx.x;   // 208*256 = 53248 exact
    if (gid < 49152) {
        int t = gid >> 14;
        int rem = gid & 16383;
        int n = rem >> 8, k = rem & 255;
        const float* W = (t == 0) ? Wq : ((t == 1) ? Wk : Wv);
        wt[gid] = (HALF)W[k * 64 + n];
    } else {
        int rem = gid - 49152;
        int n = rem >> 6, k = rem & 63;
        wto[rem] = (HALF)Wo[k * 64 + n];
    }
}

// ---------------- kernel 1: projections ----------------
// Emits q_h/k_h row-major f16, v transposed vt[b][dv][key] f16,
// kc[b][key] = -0.125*||k_row||^2 for valid keys, -inf for masked keys.
__global__ __launch_bounds__(256, 2) void k_proj(const float* __restrict__ qs,
                                                 const float* __restrict__ ks,
                                                 const float* __restrict__ vs,
                                                 const float* __restrict__ bq,
                                                 const float* __restrict__ bk,
                                                 const float* __restrict__ bv,
                                                 const int* __restrict__ vlen,
                                                 const HALF* __restrict__ wt,
                                                 HALF* __restrict__ qh,
                                                 HALF* __restrict__ kh,
                                                 HALF* __restrict__ vth,
                                                 float* __restrict__ kcw) {
    int bid = blockIdx.x;
    int t = bid >> 9;           // which projection
    int rem = bid & 511;
    int b = rem & 7, rt = rem >> 3;
    int m0 = rt * 64;
    const float* X    = (t == 0) ? qs : ((t == 1) ? ks : vs);
    const float* bias = (t == 0) ? bq : ((t == 1) ? bk : bv);
    int valid = vlen[b];

    __shared__ char smem[67584];
    HALF (*sW)[264]  = (HALF(*)[264])smem;             // 33792 B
    HALF (*sX)[264]  = (HALF(*)[264])(smem + 33792);   // 33792 B
    float (*sOut)[68] = (float(*)[68])(smem + 33792);  // overlaps sX

    int tid = threadIdx.x;
    int w = tid >> 6, lane = tid & 63, ln = lane & 15, quad = lane >> 4;

    const HALF* wsrc = wt + t * 16384;
#pragma unroll
    for (int s = 0; s < 8; ++s) {
        int flat = (s * 256 + tid) * 8;
        int r = flat >> 8, c = flat & 255;
        *(uint4*)&sW[r][c] = *(const uint4*)(wsrc + flat);
    }
    const float* xbase = X + ((size_t)(b * 4096 + m0)) * 256;
#pragma unroll
    for (int s = 0; s < 16; ++s) {
        int flat = (s * 256 + tid) * 4;
        int r = flat >> 8, c = flat & 255;
        float4 xv = *(const float4*)(xbase + flat);
        Cv4 cv; cv.h[0] = (HALF)xv.x; cv.h[1] = (HALF)xv.y;
        cv.h[2] = (HALF)xv.z; cv.h[3] = (HALF)xv.w;
        *(uint2*)&sX[r][c] = cv.u;
    }
    __syncthreads();

    f32x4 zero4 = {0.f, 0.f, 0.f, 0.f};
    f32x4 acc[4] = {zero4, zero4, zero4, zero4};
#pragma unroll
    for (int kb = 0; kb < 8; ++kb) {
        half8 a = *(half8*)&sX[w * 16 + ln][kb * 32 + quad * 8];
#pragma unroll
        for (int t4 = 0; t4 < 4; ++t4) {
            half8 bf = *(half8*)&sW[t4 * 16 + ln][kb * 32 + quad * 8];
            acc[t4] = MFMA32(a, bf, acc[t4]);
        }
    }
    __syncthreads();   // done reading sX; reuse as sOut

    float bias_v[4];
#pragma unroll
    for (int t4 = 0; t4 < 4; ++t4) bias_v[t4] = bias[t4 * 16 + ln];

    float rsq[4] = {0.f, 0.f, 0.f, 0.f};
#pragma unroll
    for (int t4 = 0; t4 < 4; ++t4) {
#pragma unroll
        for (int r = 0; r < 4; ++r) {
            float v = acc[t4][r] + bias_v[t4];
            rsq[r] += v * v;
            sOut[w * 16 + quad * 4 + r][t4 * 16 + ln] = v;
        }
    }
    if (t == 1) {
#pragma unroll
        for (int r = 0; r < 4; ++r) {
            float v = rsq[r];
#pragma unroll
            for (int off = 1; off < 16; off <<= 1) v += __shfl_xor(v, off);
            if (ln == 0) {
                int kidx = m0 + w * 16 + quad * 4 + r;
                kcw[b * 4096 + kidx] = (kidx < valid) ? -0.125f * v : -__builtin_inff();
            }
        }
    }
    __syncthreads();

    if (t < 2) {
        HALF* dst = ((t == 0) ? qh : kh) + ((size_t)(b * 4096 + m0)) * 64;
#pragma unroll
        for (int s = 0; s < 4; ++s) {
            int flat = (s * 256 + tid) * 4;
            int r = flat >> 6, c = flat & 63;
            float4 v = *(float4*)&sOut[r][c];
            Cv4 cv; cv.h[0] = (HALF)v.x; cv.h[1] = (HALF)v.y;
            cv.h[2] = (HALF)v.z; cv.h[3] = (HALF)v.w;
            *(uint2*)(dst + flat) = cv.u;
        }
    } else {
        HALF* dst = vth + (size_t)b * 64 * 4096 + m0;
#pragma unroll
        for (int s = 0; s < 2; ++s) {
            int dv = s * 32 + (tid >> 3);
            int kc = (tid & 7) * 8;
            Cv8 cv;
#pragma unroll
            for (int i = 0; i < 8; ++i) cv.h[i] = (HALF)sOut[kc + i][dv];
            *(uint4*)(dst + (size_t)dv * 4096 + kc) = cv.u;
        }
    }
}

// ---------------- kernel 2: K-sliced two-pass RBF attention ----------------
// Block = 4 waves on 16 q-rows; wave w handles K-tiles nt%4==w.
// grid = 8 batches * 256 row-groups = 2048 blocks (32 waves/CU).
__global__ __launch_bounds__(256, 8) void k_attn(const HALF* __restrict__ qh,
                                                 const HALF* __restrict__ kh,
                                                 const HALF* __restrict__ vth,
                                                 const float* __restrict__ kcw,
                                                 const int* __restrict__ vlen,
                                                 const HALF* __restrict__ wto,
                                                 const float* __restrict__ bo,
                                                 float* __restrict__ attn_out,
                                                 float* __restrict__ out) {
    int bid = blockIdx.x;
    int rg  = bid >> 3;                      // 16-row group within batch (0..255)
    int b   = (bid & 7) ^ ((rg & 1) << 2);   // 2 batches per XCD: L2-fit + balance
    int m0  = rg * 16;
    int tid = threadIdx.x;
    int w = tid >> 6, lane = tid & 63, ln = lane & 15, quad = lane >> 4;
    int valid = vlen[b];
    int nvt = (valid + 63) >> 6;

    __shared__ float sCtx[4][64][17];        // 17408 B (pad 17 -> <=2-way conflicts)
    __shared__ float sRS[4][16];             //   256 B

    const HALF*  kb  = kh  + (size_t)b * 262144;
    const HALF*  vtb = vth + (size_t)b * 262144;
    const float* kcb = kcw + b * 4096;

    // Q fragments (B-operand of swapped QK^T): Q[q=ln][d = chunk*32 + quad*8 + i]
    const HALF* qrow = qh + ((size_t)(b * 4096 + m0 + ln)) * 64 + quad * 8;
    half8 qb0 = *(const half8*)qrow;
    half8 qb1 = *(const half8*)(qrow + 32);

    const HALF* kfb = kb + (size_t)ln * 64 + quad * 8;   // K A-frag base
    f32x4 zz = {0.f, 0.f, 0.f, 0.f};

    // ---- pass A: partial row sums over this wave's tile slice ----
    float rs = 0.f;
    if (w < nvt) {
        half8 ka[4][2];
        const HALF* kf0 = kfb + (size_t)(w << 6) * 64;
#pragma unroll
        for (int t4 = 0; t4 < 4; ++t4) {
            ka[t4][0] = *(const half8*)(kf0 + t4 * 1024);
            ka[t4][1] = *(const half8*)(kf0 + t4 * 1024 + 32);
        }
        for (int nt = w; nt < nvt; nt += 4) {
            const float* kcp = kcb + (nt << 6) + quad * 4;
            f32x4 acc[4];
#pragma unroll
            for (int t4 = 0; t4 < 4; ++t4) {
                acc[t4] = MFMA32(ka[t4][0], qb0, zz);
                acc[t4] = MFMA32(ka[t4][1], qb1, acc[t4]);
            }
            int n1 = (nt + 4 < nvt ? nt + 4 : nt) << 6;
            const HALF* kf = kfb + (size_t)n1 * 64;
#pragma unroll
            for (int t4 = 0; t4 < 4; ++t4) {
                ka[t4][0] = *(const half8*)(kf + t4 * 1024);
                ka[t4][1] = *(const half8*)(kf + t4 * 1024 + 32);
            }
#pragma unroll
            for (int t4 = 0; t4 < 4; ++t4) {
                f32x4 kcv = *(const f32x4*)(kcp + t4 * 16);
#pragma unroll
                for (int r = 0; r < 4; ++r)
                    rs += __expf(fmaf(acc[t4][r], 0.25f, kcv[r]));
            }
        }
    }
    rs += __shfl_xor(rs, 16);
    rs += __shfl_xor(rs, 32);
    if (quad == 0) sRS[w][ln] = rs;
    __syncthreads();
    float inv = 1.0f / (sRS[0][ln] + sRS[1][ln] + sRS[2][ln] + sRS[3][ln]);

    // ---- pass B: recompute, normalize, store attn (nontemporal), partial PV ----
    f32x4 cacc[4] = {zz, zz, zz, zz};
    float* arow = attn_out + ((size_t)(b * 4096 + m0 + ln)) * 4096 + quad * 4;
    const HALF* vfb = vtb + (size_t)ln * 4096 + quad * 4;  // V^T A-frag base

    if (w < nvt) {
        half8 ka[4][2];
        const HALF* kf0 = kfb + (size_t)(w << 6) * 64;
#pragma unroll
        for (int t4 = 0; t4 < 4; ++t4) {
            ka[t4][0] = *(const half8*)(kf0 + t4 * 1024);
            ka[t4][1] = *(const half8*)(kf0 + t4 * 1024 + 32);
        }
        for (int nt = w; nt < nvt; nt += 4) {
            int n0 = nt << 6;
            // V fragments for this tile (consumed at the end -> latency hidden)
            half4 va[4][4];
#pragma unroll
            for (int t4dv = 0; t4dv < 4; ++t4dv)
#pragma unroll
                for (int t4k = 0; t4k < 4; ++t4k)
                    va[t4dv][t4k] = *(const half4*)(vfb + (size_t)t4dv * 65536 + n0 + t4k * 16);

            f32x4 acc[4];
#pragma unroll
            for (int t4 = 0; t4 < 4; ++t4) {
                acc[t4] = MFMA32(ka[t4][0], qb0, zz);
                acc[t4] = MFMA32(ka[t4][1], qb1, acc[t4]);
            }
            int n1 = (nt + 4 < nvt ? nt + 4 : nt) << 6;
            const HALF* kf = kfb + (size_t)n1 * 64;
#pragma unroll
            for (int t4 = 0; t4 < 4; ++t4) {
                ka[t4][0] = *(const half8*)(kf + t4 * 1024);
                ka[t4][1] = *(const half8*)(kf + t4 * 1024 + 32);
            }

            const float* kcp = kcb + n0 + quad * 4;
            half4 pb[4];
#pragma unroll
            for (int t4 = 0; t4 < 4; ++t4) {
                f32x4 kcv = *(const f32x4*)(kcp + t4 * 16);
                f32x4 p;
#pragma unroll
                for (int r = 0; r < 4; ++r)
                    p[r] = __expf(fmaf(acc[t4][r], 0.25f, kcv[r])) * inv;
                __builtin_nontemporal_store(p, (f32x4*)(arow + n0 + t4 * 16));
                PK4 pk;
                pk.p2[0] = __builtin_amdgcn_cvt_pkrtz(p[0], p[1]);
                pk.p2[1] = __builtin_amdgcn_cvt_pkrtz(p[2], p[3]);
                pb[t4] = pk.v;
            }
#pragma unroll
            for (int t4dv = 0; t4dv < 4; ++t4dv)
#pragma unroll
                for (int t4k = 0; t4k < 4; ++t4k)
                    cacc[t4dv] = MFMA16(va[t4dv][t4k], pb[t4k], cacc[t4dv]);
        }
    }

    // ---- masked tiles in this wave's slice: pure zero streams ----
    {
        int j0 = (nvt > w) ? ((nvt - w + 3) >> 2) : 0;
        for (int nt = w + (j0 << 2); nt < 64; nt += 4) {
#pragma unroll
            for (int t4 = 0; t4 < 4; ++t4)
                __builtin_nontemporal_store(zz, (f32x4*)(arow + (nt << 6) + t4 * 16));
        }
    }

    // ---- combine partial PV across waves, then Wo epilogue (wave w -> t4o=w) ----
#pragma unroll
    for (int t4dv = 0; t4dv < 4; ++t4dv)
#pragma unroll
        for (int r = 0; r < 4; ++r)
            sCtx[w][t4dv * 16 + quad * 4 + r][ln] = cacc[t4dv][r];
    __syncthreads();

    half4 cb[4];
#pragma unroll
    for (int t4c = 0; t4c < 4; ++t4c) {
        float s[4];
#pragma unroll
        for (int i = 0; i < 4; ++i) {
            int dv = t4c * 16 + quad * 4 + i;
            s[i] = sCtx[0][dv][ln] + sCtx[1][dv][ln] + sCtx[2][dv][ln] + sCtx[3][dv][ln];
        }
        PK4 pk;
        pk.p2[0] = __builtin_amdgcn_cvt_pkrtz(s[0], s[1]);
        pk.p2[1] = __builtin_amdgcn_cvt_pkrtz(s[2], s[3]);
        cb[t4c] = pk.v;
    }
    f32x4 oacc = zz;
    const HALF* wfb = wto + (size_t)(w * 16 + ln) * 64 + quad * 4;
#pragma unroll
    for (int t4c = 0; t4c < 4; ++t4c) {
        half4 wa = *(const half4*)(wfb + t4c * 16);
        oacc = MFMA16(wa, cb[t4c], oacc);
    }
    f32x4 bo4 = *(const f32x4*)(bo + w * 16 + quad * 4);
    f32x4 ov = oacc + bo4;
    *(f32x4*)(out + ((size_t)(b * 4096 + m0 + ln)) * 64 + w * 16 + quad * 4) = ov;
}

// ---------------- launch ----------------
extern "C" void kernel_launch(void* const* d_in, const int* in_sizes, int n_in,
                              void* d_out, int out_size, void* d_ws, size_t ws_size,
                              hipStream_t stream) {
    const float* qs = (const float*)d_in[0];
    const float* ks = (const float*)d_in[1];
    const float* vs = (const float*)d_in[2];
    const int* vlen = (const int*)d_in[3];
    const float* Wq = (const float*)d_in[4];
    const float* bq = (const float*)d_in[5];
    const float* Wk = (const float*)d_in[6];
    const float* bk = (const float*)d_in[7];
    const float* Wv = (const float*)d_in[8];
    const float* bv = (const float*)d_in[9];
    const float* Wo = (const float*)d_in[10];
    const float* bo = (const float*)d_in[11];

    float* out  = (float*)d_out;            // [8,4096,64]
    float* attn = out + 2097152;            // [8,4096,4096]

    char* wsb = (char*)d_ws;
    HALF*  wt  = (HALF*)(wsb + 0);          //  98304 B : W^T f16 (q,k,v)
    HALF*  wto = (HALF*)(wsb + 98304);      //   8192 B : Wo^T f16
    HALF*  qh  = (HALF*)(wsb + 131072);     //   4 MB   : q f16 [b][m][64]
    HALF*  kh  = (HALF*)(wsb + 4325376);    //   4 MB   : k f16 [b][n][64]
    HALF*  vth = (HALF*)(wsb + 8519680);    //   4 MB   : v^T f16 [b][dv][n]
    float* kcw = (float*)(wsb + 12713984);  // 128 KB   : -0.125*||k||^2 (-inf masked)

    k_prep<<<208, 256, 0, stream>>>(Wq, Wk, Wv, Wo, wt, wto);
    k_proj<<<1536, 256, 0, stream>>>(qs, ks, vs, bq, bk, bv, vlen, wt, qh, kh, vth, kcw);
    k_attn<<<2048, 256, 0, stream>>>(qh, kh, vth, kcw, vlen, wto, bo, attn, out);
}

// Round 3
// 996.230 us; speedup vs baseline: 1.0114x; 1.0114x over previous
//
#include <hip/hip_runtime.h>
#include <hip/hip_bf16.h>

// RBF-kernel attention, MI355X.  B=8, Q=K=4096, D=256, d=64.
// Outputs (concat fp32): out [8,4096,64] then attn [8,4096,4096].
// R6 = R5 with two changes (A/B vs R5):
//  - PLAIN stores for attn + zero tiles (was nontemporal). R4/R5 both pinned at
//    ~1.4 TB/s regardless of 4x occupancy change => shared saturated resource =
//    the NT store path (bypasses L2 write-combining; acks at HBM latency into
//    the vmcnt FIFO). Plain stores through L2 merge t4-adjacent 64B segments
//    into full lines and write back at stream rate (fill kernel: 6.2 TB/s).
//  - launch_bounds(256,6) (was (256,8)): R5's forced VGPR=32 starved the
//    kernel (operands bounced through AGPRs). Occupancy was not the limiter.
// Structure (from R5): block = 4 waves on the SAME 16 q-rows; wave w takes
// K-tiles nt%4==w. 8192 waves. Swapped QK^T (mfma(K,Q^T)) so lane owns one
// q-row's scores; P feeds PV via mfma_16x16x16f16 with 2 cvt_pkrtz, no
// shuffles; rowsum combine 256B LDS; PV combine via padded LDS slab; mask
// baked into kcw (-inf).

typedef _Float16 HALF;
typedef HALF half8 __attribute__((ext_vector_type(8)));
typedef HALF half4 __attribute__((ext_vector_type(4)));
typedef __fp16 fp16x2 __attribute__((ext_vector_type(2)));
typedef float f32x4 __attribute__((ext_vector_type(4)));

#define MFMA32(a, b, c) __builtin_amdgcn_mfma_f32_16x16x32_f16((a), (b), (c), 0, 0, 0)
#define MFMA16(a, b, c) __builtin_amdgcn_mfma_f32_16x16x16f16((a), (b), (c), 0, 0, 0)

union Cv4 { HALF h[4]; uint2 u; };
union Cv8 { HALF h[8]; uint4 u; };
union PK4 { fp16x2 p2[2]; half4 v; };

// ---------------- kernel 0: W transposes -> f16 ----------------
__global__ __launch_bounds__(256) void k_prep(const float* __restrict__ Wq,
                                              const float* __restrict__ Wk,
                                              const float* __restrict__ Wv,
                                              const float* __restrict__ Wo,
                                              HALF* __restrict__ wt,
                                              HALF* __restrict__ wto) {
    int gid = blockIdx.x * 256 + threadIdx.x;   // 208*256 = 53248 exact
    if (gid < 49152) {
        int t = gid >> 14;
        int rem = gid & 16383;
        int n = rem >> 8, k = rem & 255;
        const float* W = (t == 0) ? Wq : ((t == 1) ? Wk : Wv);
        wt[gid] = (HALF)W[k * 64 + n];
    } else {
        int rem = gid - 49152;
        int n = rem >> 6, k = rem & 63;
        wto[rem] = (HALF)Wo[k * 64 + n];
    }
}

// ---------------- kernel 1: projections ----------------
// Emits q_h/k_h row-major f16, v transposed vt[b][dv][key] f16,
// kc[b][key] = -0.125*||k_row||^2 for valid keys, -inf for masked keys.
__global__ __launch_bounds__(256, 2) void k_proj(const float* __restrict__ qs,
                                                 const float* __restrict__ ks,
                                                 const float* __restrict__ vs,
                                                 const float* __restrict__ bq,
                                                 const float* __restrict__ bk,
                                                 const float* __restrict__ bv,
                                                 const int* __restrict__ vlen,
                                                 const HALF* __restrict__ wt,
                                                 HALF* __restrict__ qh,
                                                 HALF* __restrict__ kh,
                                                 HALF* __restrict__ vth,
                                                 float* __restrict__ kcw) {
    int bid = blockIdx.x;
    int t = bid >> 9;           // which projection
    int rem = bid & 511;
    int b = rem & 7, rt = rem >> 3;
    int m0 = rt * 64;
    const float* X    = (t == 0) ? qs : ((t == 1) ? ks : vs);
    const float* bias = (t == 0) ? bq : ((t == 1) ? bk : bv);
    int valid = vlen[b];

    __shared__ char smem[67584];
    HALF (*sW)[264]  = (HALF(*)[264])smem;             // 33792 B
    HALF (*sX)[264]  = (HALF(*)[264])(smem + 33792);   // 33792 B
    float (*sOut)[68] = (float(*)[68])(smem + 33792);  // overlaps sX

    int tid = threadIdx.x;
    int w = tid >> 6, lane = tid & 63, ln = lane & 15, quad = lane >> 4;

    const HALF* wsrc = wt + t * 16384;
#pragma unroll
    for (int s = 0; s < 8; ++s) {
        int flat = (s * 256 + tid) * 8;
        int r = flat >> 8, c = flat & 255;
        *(uint4*)&sW[r][c] = *(const uint4*)(wsrc + flat);
    }
    const float* xbase = X + ((size_t)(b * 4096 + m0)) * 256;
#pragma unroll
    for (int s = 0; s < 16; ++s) {
        int flat = (s * 256 + tid) * 4;
        int r = flat >> 8, c = flat & 255;
        float4 xv = *(const float4*)(xbase + flat);
        Cv4 cv; cv.h[0] = (HALF)xv.x; cv.h[1] = (HALF)xv.y;
        cv.h[2] = (HALF)xv.z; cv.h[3] = (HALF)xv.w;
        *(uint2*)&sX[r][c] = cv.u;
    }
    __syncthreads();

    f32x4 zero4 = {0.f, 0.f, 0.f, 0.f};
    f32x4 acc[4] = {zero4, zero4, zero4, zero4};
#pragma unroll
    for (int kb = 0; kb < 8; ++kb) {
        half8 a = *(half8*)&sX[w * 16 + ln][kb * 32 + quad * 8];
#pragma unroll
        for (int t4 = 0; t4 < 4; ++t4) {
            half8 bf = *(half8*)&sW[t4 * 16 + ln][kb * 32 + quad * 8];
            acc[t4] = MFMA32(a, bf, acc[t4]);
        }
    }
    __syncthreads();   // done reading sX; reuse as sOut

    float bias_v[4];
#pragma unroll
    for (int t4 = 0; t4 < 4; ++t4) bias_v[t4] = bias[t4 * 16 + ln];

    float rsq[4] = {0.f, 0.f, 0.f, 0.f};
#pragma unroll
    for (int t4 = 0; t4 < 4; ++t4) {
#pragma unroll
        for (int r = 0; r < 4; ++r) {
            float v = acc[t4][r] + bias_v[t4];
            rsq[r] += v * v;
            sOut[w * 16 + quad * 4 + r][t4 * 16 + ln] = v;
        }
    }
    if (t == 1) {
#pragma unroll
        for (int r = 0; r < 4; ++r) {
            float v = rsq[r];
#pragma unroll
            for (int off = 1; off < 16; off <<= 1) v += __shfl_xor(v, off);
            if (ln == 0) {
                int kidx = m0 + w * 16 + quad * 4 + r;
                kcw[b * 4096 + kidx] = (kidx < valid) ? -0.125f * v : -__builtin_inff();
            }
        }
    }
    __syncthreads();

    if (t < 2) {
        HALF* dst = ((t == 0) ? qh : kh) + ((size_t)(b * 4096 + m0)) * 64;
#pragma unroll
        for (int s = 0; s < 4; ++s) {
            int flat = (s * 256 + tid) * 4;
            int r = flat >> 6, c = flat & 63;
            float4 v = *(float4*)&sOut[r][c];
            Cv4 cv; cv.h[0] = (HALF)v.x; cv.h[1] = (HALF)v.y;
            cv.h[2] = (HALF)v.z; cv.h[3] = (HALF)v.w;
            *(uint2*)(dst + flat) = cv.u;
        }
    } else {
        HALF* dst = vth + (size_t)b * 64 * 4096 + m0;
#pragma unroll
        for (int s = 0; s < 2; ++s) {
            int dv = s * 32 + (tid >> 3);
            int kc = (tid & 7) * 8;
            Cv8 cv;
#pragma unroll
            for (int i = 0; i < 8; ++i) cv.h[i] = (HALF)sOut[kc + i][dv];
            *(uint4*)(dst + (size_t)dv * 4096 + kc) = cv.u;
        }
    }
}

// ---------------- kernel 2: K-sliced two-pass RBF attention ----------------
// Block = 4 waves on 16 q-rows; wave w handles K-tiles nt%4==w.
// grid = 8 batches * 256 row-groups = 2048 blocks.
__global__ __launch_bounds__(256, 6) void k_attn(const HALF* __restrict__ qh,
                                                 const HALF* __restrict__ kh,
                                                 const HALF* __restrict__ vth,
                                                 const float* __restrict__ kcw,
                                                 const int* __restrict__ vlen,
                                                 const HALF* __restrict__ wto,
                                                 const float* __restrict__ bo,
                                                 float* __restrict__ attn_out,
                                                 float* __restrict__ out) {
    int bid = blockIdx.x;
    int rg  = bid >> 3;                      // 16-row group within batch (0..255)
    int b   = (bid & 7) ^ ((rg & 1) << 2);   // 2 batches per XCD: L2-fit + balance
    int m0  = rg * 16;
    int tid = threadIdx.x;
    int w = tid >> 6, lane = tid & 63, ln = lane & 15, quad = lane >> 4;
    int valid = vlen[b];
    int nvt = (valid + 63) >> 6;

    __shared__ float sCtx[4][64][17];        // 17408 B (pad 17 -> <=2-way conflicts)
    __shared__ float sRS[4][16];             //   256 B

    const HALF*  kb  = kh  + (size_t)b * 262144;
    const HALF*  vtb = vth + (size_t)b * 262144;
    const float* kcb = kcw + b * 4096;

    // Q fragments (B-operand of swapped QK^T): Q[q=ln][d = chunk*32 + quad*8 + i]
    const HALF* qrow = qh + ((size_t)(b * 4096 + m0 + ln)) * 64 + quad * 8;
    half8 qb0 = *(const half8*)qrow;
    half8 qb1 = *(const half8*)(qrow + 32);

    const HALF* kfb = kb + (size_t)ln * 64 + quad * 8;   // K A-frag base
    f32x4 zz = {0.f, 0.f, 0.f, 0.f};

    // ---- pass A: partial row sums over this wave's tile slice ----
    float rs = 0.f;
    if (w < nvt) {
        half8 ka[4][2];
        const HALF* kf0 = kfb + (size_t)(w << 6) * 64;
#pragma unroll
        for (int t4 = 0; t4 < 4; ++t4) {
            ka[t4][0] = *(const half8*)(kf0 + t4 * 1024);
            ka[t4][1] = *(const half8*)(kf0 + t4 * 1024 + 32);
        }
        for (int nt = w; nt < nvt; nt += 4) {
            const float* kcp = kcb + (nt << 6) + quad * 4;
            f32x4 acc[4];
#pragma unroll
            for (int t4 = 0; t4 < 4; ++t4) {
                acc[t4] = MFMA32(ka[t4][0], qb0, zz);
                acc[t4] = MFMA32(ka[t4][1], qb1, acc[t4]);
            }
            int n1 = (nt + 4 < nvt ? nt + 4 : nt) << 6;
            const HALF* kf = kfb + (size_t)n1 * 64;
#pragma unroll
            for (int t4 = 0; t4 < 4; ++t4) {
                ka[t4][0] = *(const half8*)(kf + t4 * 1024);
                ka[t4][1] = *(const half8*)(kf + t4 * 1024 + 32);
            }
#pragma unroll
            for (int t4 = 0; t4 < 4; ++t4) {
                f32x4 kcv = *(const f32x4*)(kcp + t4 * 16);
#pragma unroll
                for (int r = 0; r < 4; ++r)
                    rs += __expf(fmaf(acc[t4][r], 0.25f, kcv[r]));
            }
        }
    }
    rs += __shfl_xor(rs, 16);
    rs += __shfl_xor(rs, 32);
    if (quad == 0) sRS[w][ln] = rs;
    __syncthreads();
    float inv = 1.0f / (sRS[0][ln] + sRS[1][ln] + sRS[2][ln] + sRS[3][ln]);

    // ---- pass B: recompute, normalize, store attn (plain), partial PV ----
    f32x4 cacc[4] = {zz, zz, zz, zz};
    float* arow = attn_out + ((size_t)(b * 4096 + m0 + ln)) * 4096 + quad * 4;
    const HALF* vfb = vtb + (size_t)ln * 4096 + quad * 4;  // V^T A-frag base

    if (w < nvt) {
        half8 ka[4][2];
        const HALF* kf0 = kfb + (size_t)(w << 6) * 64;
#pragma unroll
        for (int t4 = 0; t4 < 4; ++t4) {
            ka[t4][0] = *(const half8*)(kf0 + t4 * 1024);
            ka[t4][1] = *(const half8*)(kf0 + t4 * 1024 + 32);
        }
        for (int nt = w; nt < nvt; nt += 4) {
            int n0 = nt << 6;
            // V fragments for this tile (consumed at the end -> latency hidden)
            half4 va[4][4];
#pragma unroll
            for (int t4dv = 0; t4dv < 4; ++t4dv)
#pragma unroll
                for (int t4k = 0; t4k < 4; ++t4k)
                    va[t4dv][t4k] = *(const half4*)(vfb + (size_t)t4dv * 65536 + n0 + t4k * 16);

            f32x4 acc[4];
#pragma unroll
            for (int t4 = 0; t4 < 4; ++t4) {
                acc[t4] = MFMA32(ka[t4][0], qb0, zz);
                acc[t4] = MFMA32(ka[t4][1], qb1, acc[t4]);
            }
            int n1 = (nt + 4 < nvt ? nt + 4 : nt) << 6;
            const HALF* kf = kfb + (size_t)n1 * 64;
#pragma unroll
            for (int t4 = 0; t4 < 4; ++t4) {
                ka[t4][0] = *(const half8*)(kf + t4 * 1024);
                ka[t4][1] = *(const half8*)(kf + t4 * 1024 + 32);
            }

            const float* kcp = kcb + n0 + quad * 4;
            half4 pb[4];
#pragma unroll
            for (int t4 = 0; t4 < 4; ++t4) {
                f32x4 kcv = *(const f32x4*)(kcp + t4 * 16);
                f32x4 p;
#pragma unroll
                for (int r = 0; r < 4; ++r)
                    p[r] = __expf(fmaf(acc[t4][r], 0.25f, kcv[r])) * inv;
                *(f32x4*)(arow + n0 + t4 * 16) = p;
                PK4 pk;
                pk.p2[0] = __builtin_amdgcn_cvt_pkrtz(p[0], p[1]);
                pk.p2[1] = __builtin_amdgcn_cvt_pkrtz(p[2], p[3]);
                pb[t4] = pk.v;
            }
#pragma unroll
            for (int t4dv = 0; t4dv < 4; ++t4dv)
#pragma unroll
                for (int t4k = 0; t4k < 4; ++t4k)
                    cacc[t4dv] = MFMA16(va[t4dv][t4k], pb[t4k], cacc[t4dv]);
        }
    }

    // ---- masked tiles in this wave's slice: pure zero streams ----
    {
        int j0 = (nvt > w) ? ((nvt - w + 3) >> 2) : 0;
        for (int nt = w + (j0 << 2); nt < 64; nt += 4) {
#pragma unroll
            for (int t4 = 0; t4 < 4; ++t4)
                *(f32x4*)(arow + (nt << 6) + t4 * 16) = zz;
        }
    }

    // ---- combine partial PV across waves, then Wo epilogue (wave w -> t4o=w) ----
#pragma unroll
    for (int t4dv = 0; t4dv < 4; ++t4dv)
#pragma unroll
        for (int r = 0; r < 4; ++r)
            sCtx[w][t4dv * 16 + quad * 4 + r][ln] = cacc[t4dv][r];
    __syncthreads();

    half4 cb[4];
#pragma unroll
    for (int t4c = 0; t4c < 4; ++t4c) {
        float s[4];
#pragma unroll
        for (int i = 0; i < 4; ++i) {
            int dv = t4c * 16 + quad * 4 + i;
            s[i] = sCtx[0][dv][ln] + sCtx[1][dv][ln] + sCtx[2][dv][ln] + sCtx[3][dv][ln];
        }
        PK4 pk;
        pk.p2[0] = __builtin_amdgcn_cvt_pkrtz(s[0], s[1]);
        pk.p2[1] = __builtin_amdgcn_cvt_pkrtz(s[2], s[3]);
        cb[t4c] = pk.v;
    }
    f32x4 oacc = zz;
    const HALF* wfb = wto + (size_t)(w * 16 + ln) * 64 + quad * 4;
#pragma unroll
    for (int t4c = 0; t4c < 4; ++t4c) {
        half4 wa = *(const half4*)(wfb + t4c * 16);
        oacc = MFMA16(wa, cb[t4c], oacc);
    }
    f32x4 bo4 = *(const f32x4*)(bo + w * 16 + quad * 4);
    f32x4 ov = oacc + bo4;
    *(f32x4*)(out + ((size_t)(b * 4096 + m0 + ln)) * 64 + w * 16 + quad * 4) = ov;
}

// ---------------- launch ----------------
extern "C" void kernel_launch(void* const* d_in, const int* in_sizes, int n_in,
                              void* d_out, int out_size, void* d_ws, size_t ws_size,
                              hipStream_t stream) {
    const float* qs = (const float*)d_in[0];
    const float* ks = (const float*)d_in[1];
    const float* vs = (const float*)d_in[2];
    const int* vlen = (const int*)d_in[3];
    const float* Wq = (const float*)d_in[4];
    const float* bq = (const float*)d_in[5];
    const float* Wk = (const float*)d_in[6];
    const float* bk = (const float*)d_in[7];
    const float* Wv = (const float*)d_in[8];
    const float* bv = (const float*)d_in[9];
    const float* Wo = (const float*)d_in[10];
    const float* bo = (const float*)d_in[11];

    float* out  = (float*)d_out;            // [8,4096,64]
    float* attn = out + 2097152;            // [8,4096,4096]

    char* wsb = (char*)d_ws;
    HALF*  wt  = (HALF*)(wsb + 0);          //  98304 B : W^T f16 (q,k,v)
    HALF*  wto = (HALF*)(wsb + 98304);      //   8192 B : Wo^T f16
    HALF*  qh  = (HALF*)(wsb + 131072);     //   4 MB   : q f16 [b][m][64]
    HALF*  kh  = (HALF*)(wsb + 4325376);    //   4 MB   : k f16 [b][n][64]
    HALF*  vth = (HALF*)(wsb + 8519680);    //   4 MB   : v^T f16 [b][dv][n]
    float* kcw = (float*)(wsb + 12713984);  // 128 KB   : -0.125*||k||^2 (-inf masked)

    k_prep<<<208, 256, 0, stream>>>(Wq, Wk, Wv, Wo, wt, wto);
    k_proj<<<1536, 256, 0, stream>>>(qs, ks, vs, bq, bk, bv, vlen, wt, qh, kh, vth, kcw);
    k_attn<<<2048, 256, 0, stream>>>(qh, kh, vth, kcw, vlen, wto, bo, attn, out);
}